// Round 2
// baseline (298.891 us; speedup 1.0000x reference)
//
#include <hip/hip_runtime.h>

typedef float f32x4 __attribute__((ext_vector_type(4)));
typedef short bf16x8 __attribute__((ext_vector_type(8)));

__device__ __forceinline__ unsigned short f2bf(float f) {
  unsigned u = __builtin_bit_cast(unsigned, f);
  u = (u + 0x7FFFu + ((u >> 16) & 1u)) >> 16;
  return (unsigned short)u;
}

// xt padded layout: [b][row 0..129][col 0..129][ch 0..127] bf16
// interior: row = y+1 (y in 0..127), col = x+1 (x in 0..127). borders zero.
#define XT_ROW 16640              // 130*128 elems per row
#define XT_B   2163200            // 130*130*128 elems per sample

// ---------------------------------------------------------------------------
// Kernel 1: x (B,C,H,W) f32 -> xt padded bf16 [b][y+1][col+1][c], + row sums
// ---------------------------------------------------------------------------
__global__ __launch_bounds__(256) void k_transpose(const float* __restrict__ x,
                                                   unsigned short* __restrict__ xt,
                                                   float* __restrict__ rowsum) {
  __shared__ unsigned short tile[128][128];
  __shared__ float psum[128][8];
  const int y = blockIdx.x, b = blockIdx.y;
  const int t = threadIdx.x;
  const int colb = (t & 7) * 16;
  const int cp = t >> 3;
  const int swz = (t & 7) << 3;
  for (int ci = 0; ci < 4; ++ci) {
    const int c = ci * 32 + cp;
    const int c2 = c ^ swz;
    const float* src = x + (((size_t)(b * 128 + c) * 128 + y) * 128 + colb);
    float s = 0.f;
#pragma unroll
    for (int j = 0; j < 16; j += 4) {
      float4 v = *(const float4*)(src + j);
      s += v.x + v.y + v.z + v.w;
      tile[colb + j + 0][c2] = f2bf(v.x);
      tile[colb + j + 1][c2] = f2bf(v.y);
      tile[colb + j + 2][c2] = f2bf(v.z);
      tile[colb + j + 3][c2] = f2bf(v.w);
    }
    psum[c][t & 7] = s;
  }
  __syncthreads();
#pragma unroll
  for (int it = 0; it < 8; ++it) {
    const int slot = t + it * 256;
    const int col = slot >> 4;
    const int cg = (slot & 15) * 8;
    const int c2 = cg ^ (((col >> 4) & 7) << 3);
    uint4 vv = *(const uint4*)&tile[col][c2];
    *(uint4*)(xt + (((size_t)b * 130 + y + 1) * 130 + col + 1) * 128 + cg) = vv;
  }
  if (t < 128) {
    float r = 0.f;
#pragma unroll
    for (int j = 0; j < 8; ++j) r += psum[t][j];
    rowsum[((size_t)b * 128 + t) * 128 + y] = r;
  }
}

// ---------------------------------------------------------------------------
// Kernel 1b: zero the padded borders of xt (rows 0,129; cols 0,129)
// per b: 2*130*16 + 128*2*16 = 8256 16B-chunks
// ---------------------------------------------------------------------------
__global__ __launch_bounds__(256) void k_border(unsigned short* __restrict__ xt) {
  const int b = blockIdx.y;
  const int idx = blockIdx.x * 256 + threadIdx.x;
  if (idx >= 8256) return;
  int row, col, ck;
  if (idx < 4160) {
    row = (idx < 2080) ? 0 : 129;
    const int s = idx % 2080;
    col = s >> 4;
    ck = s & 15;
  } else {
    const int s = idx - 4160;
    row = (s >> 5) + 1;
    col = (s & 16) ? 129 : 0;
    ck = s & 15;
  }
  uint4 z = {0, 0, 0, 0};
  *(uint4*)(xt + ((size_t)b * 130 + row) * 130 * 128 + (size_t)col * 128 + ck * 8) = z;
}

// ---------------------------------------------------------------------------
// Kernel 2: rowsums -> pooled -> attention MLP -> softmax -> attn, agg_b
// ---------------------------------------------------------------------------
__global__ __launch_bounds__(128) void k_attn(const float* __restrict__ rowsum,
                                              const float* __restrict__ aw1,
                                              const float* __restrict__ ab1,
                                              const float* __restrict__ aw2,
                                              const float* __restrict__ ab2,
                                              const float* __restrict__ bias,
                                              float* __restrict__ attn,
                                              float* __restrict__ aggb) {
  __shared__ float pooled[128];
  __shared__ float h[32];
  __shared__ float at[4];
  const int b = blockIdx.x, t = threadIdx.x;
  const float* rs = rowsum + (size_t)(b * 128 + t) * 128;
  float s = 0.f;
  for (int yy = 0; yy < 128; ++yy) s += rs[yy];
  pooled[t] = s * (1.f / 16384.f);
  __syncthreads();
  if (t < 32) {
    float hv = ab1[t];
    for (int c = 0; c < 128; ++c) hv += pooled[c] * aw1[t * 128 + c];
    h[t] = fmaxf(hv, 0.f);
  }
  __syncthreads();
  if (t < 4) {
    float sc = ab2[t];
    for (int a = 0; a < 32; ++a) sc += h[a] * aw2[t * 32 + a];
    at[t] = sc * (1.f / 30.f);
  }
  __syncthreads();
  if (t == 0) {
    float m = fmaxf(fmaxf(at[0], at[1]), fmaxf(at[2], at[3]));
    float e0 = __expf(at[0] - m), e1 = __expf(at[1] - m);
    float e2 = __expf(at[2] - m), e3 = __expf(at[3] - m);
    float inv = 1.f / (e0 + e1 + e2 + e3);
    at[0] = e0 * inv; at[1] = e1 * inv; at[2] = e2 * inv; at[3] = e3 * inv;
  }
  __syncthreads();
  if (t < 4) attn[b * 4 + t] = at[t];
  float ab = 0.f;
  for (int k = 0; k < 4; ++k) ab += at[k] * bias[k * 128 + t];
  aggb[b * 128 + t] = ab;
}

// ---------------------------------------------------------------------------
// Kernel 3: aggregate weights over K, bf16, MFMA-A layout:
//   aggw[(((b*9+pq)*4+cc)*128+o)*32 + c']
// ---------------------------------------------------------------------------
__global__ __launch_bounds__(256) void k_aggw(const float* __restrict__ weight,
                                              const float* __restrict__ attn,
                                              unsigned short* __restrict__ aggw) {
  const int fid = blockIdx.x * 256 + threadIdx.x;
  const int cl = fid & 31;
  const int o = (fid >> 5) & 127;
  const int cc = (fid >> 12) & 3;
  const int rest = fid >> 14;
  const int pq = rest % 9;
  const int b = rest / 9;
  const int c = cc * 32 + cl;
  const size_t src = (size_t)o * 1152 + (size_t)c * 9 + pq;
  float s = attn[b * 4 + 0] * weight[src]
          + attn[b * 4 + 1] * weight[src + 147456]
          + attn[b * 4 + 2] * weight[src + 2 * 147456]
          + attn[b * 4 + 3] * weight[src + 3 * 147456];
  aggw[fid] = f2bf(s);
}

// ---------------------------------------------------------------------------
// Kernel 4: conv as implicit GEMM. One block per (y,b) via XCD swizzle.
// Branchless 36-step flat K-loop (padded xt), 1-deep register pipeline.
// ---------------------------------------------------------------------------
__global__ __launch_bounds__(256, 3) void k_conv(const unsigned short* __restrict__ xt,
                                                 const unsigned short* __restrict__ aggw,
                                                 const float* __restrict__ aggb,
                                                 float* __restrict__ out) {
  const int id = blockIdx.x;
  const int swz = (id & 7) * 256 + (id >> 3);   // 2048 blocks, 8 XCDs, bijective
  const int b = swz >> 7, y = swz & 127;
  const int t = threadIdx.x;
  const int lane = t & 63, wid = t >> 6;
  const int mw = wid >> 1, nw = wid & 1;
  const int l15 = lane & 15, lk = lane >> 4;

  // A: per-step stride 4096 elems; frag = base + mi*512
  const unsigned short* ap = aggw + (size_t)b * 147456 + l15 * 32 + lk * 8 + mw * 2048;
  // B: base at (row y+0 pad, col = nw*64+l15+1), per-step offset
  //    p*XT_ROW + (q-1)*128 + cc*32, frag = +ni*2048
  const unsigned short* xb = xt + ((size_t)b * 130 + y) * XT_ROW
                           + (size_t)(nw * 64 + l15 + 1) * 128 + lk * 8;

  f32x4 acc[4][4] = {};
  bf16x8 aC[4], bC[4], aN[4], bN[4];
#pragma unroll
  for (int mi = 0; mi < 4; ++mi) aC[mi] = *(const bf16x8*)(ap + mi * 512);
#pragma unroll
  for (int ni = 0; ni < 4; ++ni) bC[ni] = *(const bf16x8*)(xb - 128 + ni * 2048);

#pragma unroll
  for (int s = 0; s < 36; ++s) {
    const int sn = s + 1;
    if (sn < 36) {
      const int p = sn / 12, q = (sn / 4) % 3, cc = sn & 3;
      const unsigned short* an = ap + sn * 4096;
#pragma unroll
      for (int mi = 0; mi < 4; ++mi) aN[mi] = *(const bf16x8*)(an + mi * 512);
      const unsigned short* bn = xb + p * XT_ROW + (q - 1) * 128 + cc * 32;
#pragma unroll
      for (int ni = 0; ni < 4; ++ni) bN[ni] = *(const bf16x8*)(bn + ni * 2048);
    }
#pragma unroll
    for (int mi = 0; mi < 4; ++mi)
#pragma unroll
      for (int ni = 0; ni < 4; ++ni)
        acc[mi][ni] = __builtin_amdgcn_mfma_f32_16x16x32_bf16(aC[mi], bC[ni], acc[mi][ni], 0, 0, 0);
#pragma unroll
    for (int i = 0; i < 4; ++i) { aC[i] = aN[i]; bC[i] = bN[i]; }
  }

  // epilogue: C/D col = lane&15 (px), row = (lane>>4)*4 + r (Cout)
  const int colb = nw * 64 + l15;
#pragma unroll
  for (int mi = 0; mi < 4; ++mi) {
    const int o = mw * 64 + mi * 16 + lk * 4;
#pragma unroll
    for (int r = 0; r < 4; ++r) {
      const float bsv = aggb[b * 128 + o + r];
      float* orow = out + ((size_t)(b * 128 + o + r) * 128 + y) * 128 + colb;
      orow[0]  = acc[mi][0][r] + bsv;
      orow[16] = acc[mi][1][r] + bsv;
      orow[32] = acc[mi][2][r] + bsv;
      orow[48] = acc[mi][3][r] + bsv;
    }
  }
}

// ---------------------------------------------------------------------------
extern "C" void kernel_launch(void* const* d_in, const int* in_sizes, int n_in,
                              void* d_out, int out_size, void* d_ws, size_t ws_size,
                              hipStream_t stream) {
  const float* x      = (const float*)d_in[0];
  const float* weight = (const float*)d_in[1];
  const float* bias   = (const float*)d_in[2];
  const float* aw1    = (const float*)d_in[3];
  const float* ab1    = (const float*)d_in[4];
  const float* aw2    = (const float*)d_in[5];
  const float* ab2    = (const float*)d_in[6];
  float* out = (float*)d_out;

  char* ws = (char*)d_ws;
  unsigned short* xt   = (unsigned short*)ws;                        // 69,222,400 B
  unsigned short* aggw = (unsigned short*)(ws + 69222400);           //  4,718,592 B
  float* rowsum        = (float*)(ws + 69222400 + 4718592);          //  1,048,576 B
  float* attn          = (float*)(ws + 69222400 + 4718592 + 1048576);         // 256 B
  float* aggb          = (float*)(ws + 69222400 + 4718592 + 1048576 + 256);   // 8 KB

  hipLaunchKernelGGL(k_border, dim3(33, 16), dim3(256), 0, stream, xt);
  hipLaunchKernelGGL(k_transpose, dim3(128, 16), dim3(256), 0, stream, x, xt, rowsum);
  hipLaunchKernelGGL(k_attn, dim3(16), dim3(128), 0, stream,
                     rowsum, aw1, ab1, aw2, ab2, bias, attn, aggb);
  hipLaunchKernelGGL(k_aggw, dim3(9216), dim3(256), 0, stream, weight, attn, aggw);
  hipLaunchKernelGGL(k_conv, dim3(2048), dim3(256), 0, stream, xt, aggw, aggb, out);
}

// Round 4
// 213.661 us; speedup vs baseline: 1.3989x; 1.3989x over previous
//
#include <hip/hip_runtime.h>

typedef float f32x4 __attribute__((ext_vector_type(4)));
typedef short bf16x8 __attribute__((ext_vector_type(8)));

__device__ __forceinline__ unsigned short f2bf(float f) {
  unsigned u = __builtin_bit_cast(unsigned, f);
  u = (u + 0x7FFFu + ((u >> 16) & 1u)) >> 16;
  return (unsigned short)u;
}

// async global->LDS, 16B per lane. LDS dest = wave-uniform base + lane*16B.
__device__ __forceinline__ void async16(const unsigned short* g, unsigned short* l) {
  __builtin_amdgcn_global_load_lds(
      (__attribute__((address_space(1))) void*)g,
      (__attribute__((address_space(3))) void*)l, 16, 0, 0);
}

// xt padded layout: [b][row 0..129][col 0..129][ch 0..127] bf16, borders zero.
#define XT_ROW 16640              // 130*128 elems per padded row

// ---------------------------------------------------------------------------
// Kernel 1: x (B,C,H,W) f32 -> xt padded bf16 [b][y+1][col+1][c], + row sums
// ---------------------------------------------------------------------------
__global__ __launch_bounds__(256) void k_transpose(const float* __restrict__ x,
                                                   unsigned short* __restrict__ xt,
                                                   float* __restrict__ rowsum) {
  __shared__ unsigned short tile[128][128];
  __shared__ float psum[128][8];
  const int y = blockIdx.x, b = blockIdx.y;
  const int t = threadIdx.x;
  const int colb = (t & 7) * 16;
  const int cp = t >> 3;
  const int swz = (t & 7) << 3;
  for (int ci = 0; ci < 4; ++ci) {
    const int c = ci * 32 + cp;
    const int c2 = c ^ swz;
    const float* src = x + (((size_t)(b * 128 + c) * 128 + y) * 128 + colb);
    float s = 0.f;
#pragma unroll
    for (int j = 0; j < 16; j += 4) {
      float4 v = *(const float4*)(src + j);
      s += v.x + v.y + v.z + v.w;
      tile[colb + j + 0][c2] = f2bf(v.x);
      tile[colb + j + 1][c2] = f2bf(v.y);
      tile[colb + j + 2][c2] = f2bf(v.z);
      tile[colb + j + 3][c2] = f2bf(v.w);
    }
    psum[c][t & 7] = s;
  }
  __syncthreads();
#pragma unroll
  for (int it = 0; it < 8; ++it) {
    const int slot = t + it * 256;
    const int col = slot >> 4;
    const int cg = (slot & 15) * 8;
    const int c2 = cg ^ (((col >> 4) & 7) << 3);
    uint4 vv = *(const uint4*)&tile[col][c2];
    *(uint4*)(xt + (((size_t)b * 130 + y + 1) * 130 + col + 1) * 128 + cg) = vv;
  }
  if (t < 128) {
    float r = 0.f;
#pragma unroll
    for (int j = 0; j < 8; ++j) r += psum[t][j];
    rowsum[((size_t)b * 128 + t) * 128 + y] = r;
  }
}

// ---------------------------------------------------------------------------
// Kernel 1b: zero the padded borders of xt
// ---------------------------------------------------------------------------
__global__ __launch_bounds__(256) void k_border(unsigned short* __restrict__ xt) {
  const int b = blockIdx.y;
  const int idx = blockIdx.x * 256 + threadIdx.x;
  if (idx >= 8256) return;
  int row, col, ck;
  if (idx < 4160) {
    row = (idx < 2080) ? 0 : 129;
    const int s = idx % 2080;
    col = s >> 4;
    ck = s & 15;
  } else {
    const int s = idx - 4160;
    row = (s >> 5) + 1;
    col = (s & 16) ? 129 : 0;
    ck = s & 15;
  }
  uint4 z = {0, 0, 0, 0};
  *(uint4*)(xt + ((size_t)b * 130 + row) * 130 * 128 + (size_t)col * 128 + ck * 8) = z;
}

// ---------------------------------------------------------------------------
// Kernel 2: rowsums -> pooled -> attention MLP -> softmax -> attn, agg_b
// ---------------------------------------------------------------------------
__global__ __launch_bounds__(128) void k_attn(const float* __restrict__ rowsum,
                                              const float* __restrict__ aw1,
                                              const float* __restrict__ ab1,
                                              const float* __restrict__ aw2,
                                              const float* __restrict__ ab2,
                                              const float* __restrict__ bias,
                                              float* __restrict__ attn,
                                              float* __restrict__ aggb) {
  __shared__ float pooled[128];
  __shared__ float h[32];
  __shared__ float at[4];
  const int b = blockIdx.x, t = threadIdx.x;
  const float* rs = rowsum + (size_t)(b * 128 + t) * 128;
  float s = 0.f;
  for (int yy = 0; yy < 128; ++yy) s += rs[yy];
  pooled[t] = s * (1.f / 16384.f);
  __syncthreads();
  if (t < 32) {
    float hv = ab1[t];
    for (int c = 0; c < 128; ++c) hv += pooled[c] * aw1[t * 128 + c];
    h[t] = fmaxf(hv, 0.f);
  }
  __syncthreads();
  if (t < 4) {
    float sc = ab2[t];
    for (int a = 0; a < 32; ++a) sc += h[a] * aw2[t * 32 + a];
    at[t] = sc * (1.f / 30.f);
  }
  __syncthreads();
  if (t == 0) {
    float m = fmaxf(fmaxf(at[0], at[1]), fmaxf(at[2], at[3]));
    float e0 = __expf(at[0] - m), e1 = __expf(at[1] - m);
    float e2 = __expf(at[2] - m), e3 = __expf(at[3] - m);
    float inv = 1.f / (e0 + e1 + e2 + e3);
    at[0] = e0 * inv; at[1] = e1 * inv; at[2] = e2 * inv; at[3] = e3 * inv;
  }
  __syncthreads();
  if (t < 4) attn[b * 4 + t] = at[t];
  float ab = 0.f;
  for (int k = 0; k < 4; ++k) ab += at[k] * bias[k * 128 + t];
  aggb[b * 128 + t] = ab;
}

// ---------------------------------------------------------------------------
// Kernel 3: aggregate weights over K, bf16, GEMM-A slab layout:
//   aggw[(((b*18 + s)*128 + o)*64 + kk)], tap=s>>1, c=(s&1)*64+kk
// ---------------------------------------------------------------------------
__global__ __launch_bounds__(256) void k_aggw(const float* __restrict__ weight,
                                              const float* __restrict__ attn,
                                              unsigned short* __restrict__ aggw) {
  const int fid = blockIdx.x * 256 + threadIdx.x;
  const int kk = fid & 63;
  const int o = (fid >> 6) & 127;
  const int rest = fid >> 13;      // b*18 + s
  const int s = rest % 18;
  const int b = rest / 18;
  const int c = ((s & 1) << 6) + kk;
  const int pq = s >> 1;
  const size_t src = (size_t)o * 1152 + (size_t)c * 9 + pq;
  float v = attn[b * 4 + 0] * weight[src]
          + attn[b * 4 + 1] * weight[src + 147456]
          + attn[b * 4 + 2] * weight[src + 2 * 147456]
          + attn[b * 4 + 3] * weight[src + 3 * 147456];
  aggw[fid] = f2bf(v);
}

// ---------------------------------------------------------------------------
// Kernel 4: conv as implicit GEMM, m97-style 2-phase double-buffered LDS.
// One block per (b,y): M=128(Cout) x N=128(cols) x K=1152, 18 steps of BK=64.
// Staging via global_load_lds width=16; one __syncthreads per K-step.
// Wave w's staging slice starts at BYTE w*1024 => ELEMENT w*512.  (r3 fix)
// ---------------------------------------------------------------------------
__global__ __launch_bounds__(256) void k_conv(const unsigned short* __restrict__ xt,
                                              const unsigned short* __restrict__ aggw,
                                              const float* __restrict__ aggb,
                                              float* __restrict__ out) {
  __shared__ unsigned short ldsA[2][8192];   // [buf][o=128][kk=64]
  __shared__ unsigned short ldsB[2][8192];   // [buf][n=128][kk=64]
  const int id = blockIdx.x;
  const int swz = (id & 7) * 256 + (id >> 3);   // 2048 % 8 == 0: bijective
  const int b = swz >> 7, y = swz & 127;
  const int t = threadIdx.x;
  const int lane = t & 63, w = t >> 6;
  const int mw = w >> 1, nw = w & 1;
  const int l15 = lane & 15, lk = lane >> 4;

  // A: per-thread source base; chunk = i*256 + t, identity map into LDS
  const unsigned short* aSrc = aggw + (size_t)b * 147456 + t * 8;
  // B: chunk = i*256 + t -> n = chunk>>3, k8 = chunk&7.
  const unsigned short* bSrc[4];
#pragma unroll
  for (int i = 0; i < 4; ++i) {
    const int chunk = i * 256 + t;
    const int n = chunk >> 3, k8 = chunk & 7;
    bSrc[i] = xt + ((size_t)(b * 130 + y) * 130 + n) * 128 + k8 * 8;
  }
  unsigned short* ldsAw = &ldsA[0][0] + w * 512;  // wave slice: byte w*1024
  unsigned short* ldsBw = &ldsB[0][0] + w * 512;

#define STAGE(buf, s) {                                                        \
    const int tap_ = (s) >> 1, c0_ = ((s) & 1) << 6;                           \
    const int p_ = tap_ / 3;                                                   \
    const int qq_ = tap_ - 3 * p_;                                             \
    _Pragma("unroll")                                                          \
    for (int i = 0; i < 4; ++i)                                                \
      async16(aSrc + (s) * 8192 + i * 2048, ldsAw + (buf) * 8192 + i * 2048);  \
    _Pragma("unroll")                                                          \
    for (int i = 0; i < 4; ++i)                                                \
      async16(bSrc[i] + p_ * XT_ROW + qq_ * 128 + c0_,                         \
              ldsBw + (buf) * 8192 + i * 2048);                                \
  }

  f32x4 acc[4][4] = {};
  STAGE(0, 0);
  __syncthreads();

#pragma unroll
  for (int s = 0; s < 18; ++s) {
    const int cur = s & 1;
    if (s + 1 < 18) STAGE(cur ^ 1, s + 1);
    const unsigned short* A0 = &ldsA[cur][0];
    const unsigned short* B0 = &ldsB[cur][0];
#pragma unroll
    for (int kk = 0; kk < 2; ++kk) {
      bf16x8 af[4], bfr[4];
#pragma unroll
      for (int mi = 0; mi < 4; ++mi)
        af[mi] = *(const bf16x8*)(A0 + (mw * 64 + mi * 16 + l15) * 64 + kk * 32 + lk * 8);
#pragma unroll
      for (int ni = 0; ni < 4; ++ni)
        bfr[ni] = *(const bf16x8*)(B0 + (nw * 64 + ni * 16 + l15) * 64 + kk * 32 + lk * 8);
#pragma unroll
      for (int mi = 0; mi < 4; ++mi)
#pragma unroll
        for (int ni = 0; ni < 4; ++ni)
          acc[mi][ni] = __builtin_amdgcn_mfma_f32_16x16x32_bf16(af[mi], bfr[ni], acc[mi][ni], 0, 0, 0);
    }
    __syncthreads();
  }
#undef STAGE

  // epilogue: C/D col = lane&15 (n/px), row = (lane>>4)*4 + r (Cout)
  const int colb = nw * 64 + l15;
#pragma unroll
  for (int mi = 0; mi < 4; ++mi) {
    const int o = mw * 64 + mi * 16 + lk * 4;
#pragma unroll
    for (int r = 0; r < 4; ++r) {
      const float bsv = aggb[b * 128 + o + r];
      float* orow = out + ((size_t)(b * 128 + o + r) * 128 + y) * 128 + colb;
      orow[0]  = acc[mi][0][r] + bsv;
      orow[16] = acc[mi][1][r] + bsv;
      orow[32] = acc[mi][2][r] + bsv;
      orow[48] = acc[mi][3][r] + bsv;
    }
  }
}

// ---------------------------------------------------------------------------
extern "C" void kernel_launch(void* const* d_in, const int* in_sizes, int n_in,
                              void* d_out, int out_size, void* d_ws, size_t ws_size,
                              hipStream_t stream) {
  const float* x      = (const float*)d_in[0];
  const float* weight = (const float*)d_in[1];
  const float* bias   = (const float*)d_in[2];
  const float* aw1    = (const float*)d_in[3];
  const float* ab1    = (const float*)d_in[4];
  const float* aw2    = (const float*)d_in[5];
  const float* ab2    = (const float*)d_in[6];
  float* out = (float*)d_out;

  char* ws = (char*)d_ws;
  unsigned short* xt   = (unsigned short*)ws;                        // 69,222,400 B
  unsigned short* aggw = (unsigned short*)(ws + 69222400);           //  4,718,592 B
  float* rowsum        = (float*)(ws + 69222400 + 4718592);          //  1,048,576 B
  float* attn          = (float*)(ws + 69222400 + 4718592 + 1048576);         // 256 B
  float* aggb          = (float*)(ws + 69222400 + 4718592 + 1048576 + 256);   // 8 KB

  hipLaunchKernelGGL(k_border, dim3(33, 16), dim3(256), 0, stream, xt);
  hipLaunchKernelGGL(k_transpose, dim3(128, 16), dim3(256), 0, stream, x, xt, rowsum);
  hipLaunchKernelGGL(k_attn, dim3(16), dim3(128), 0, stream,
                     rowsum, aw1, ab1, aw2, ab2, bias, attn, aggb);
  hipLaunchKernelGGL(k_aggw, dim3(9216), dim3(256), 0, stream, weight, attn, aggw);
  hipLaunchKernelGGL(k_conv, dim3(2048), dim3(256), 0, stream, xt, aggw, aggb, out);
}

// Round 5
// 158.294 us; speedup vs baseline: 1.8882x; 1.3498x over previous
//
#include <hip/hip_runtime.h>

typedef float f32x4 __attribute__((ext_vector_type(4)));
typedef short bf16x8 __attribute__((ext_vector_type(8)));

__device__ __forceinline__ unsigned short f2bf(float f) {
  unsigned u = __builtin_bit_cast(unsigned, f);
  u = (u + 0x7FFFu + ((u >> 16) & 1u)) >> 16;
  return (unsigned short)u;
}

// async global->LDS, 16B per lane. LDS dest = wave-uniform base + lane*16B.
__device__ __forceinline__ void async16(const unsigned short* g, unsigned short* l) {
  __builtin_amdgcn_global_load_lds(
      (__attribute__((address_space(1))) void*)g,
      (__attribute__((address_space(3))) void*)l, 16, 0, 0);
}

// xt padded layout: [b][row 0..129][col 0..129][ch 0..127] bf16, borders zero.
#define XT_ROW 16640              // 130*128 elems per padded row

// ---------------------------------------------------------------------------
// Kernel 1: x (B,C,H,W) f32 -> xt padded bf16 [b][y+1][col+1][c], + row sums
// ---------------------------------------------------------------------------
__global__ __launch_bounds__(256) void k_transpose(const float* __restrict__ x,
                                                   unsigned short* __restrict__ xt,
                                                   float* __restrict__ rowsum) {
  __shared__ unsigned short tile[128][128];
  __shared__ float psum[128][8];
  const int y = blockIdx.x, b = blockIdx.y;
  const int t = threadIdx.x;
  const int colb = (t & 7) * 16;
  const int cp = t >> 3;
  const int swz = (t & 7) << 3;
  for (int ci = 0; ci < 4; ++ci) {
    const int c = ci * 32 + cp;
    const int c2 = c ^ swz;
    const float* src = x + (((size_t)(b * 128 + c) * 128 + y) * 128 + colb);
    float s = 0.f;
#pragma unroll
    for (int j = 0; j < 16; j += 4) {
      float4 v = *(const float4*)(src + j);
      s += v.x + v.y + v.z + v.w;
      tile[colb + j + 0][c2] = f2bf(v.x);
      tile[colb + j + 1][c2] = f2bf(v.y);
      tile[colb + j + 2][c2] = f2bf(v.z);
      tile[colb + j + 3][c2] = f2bf(v.w);
    }
    psum[c][t & 7] = s;
  }
  __syncthreads();
#pragma unroll
  for (int it = 0; it < 8; ++it) {
    const int slot = t + it * 256;
    const int col = slot >> 4;
    const int cg = (slot & 15) * 8;
    const int c2 = cg ^ (((col >> 4) & 7) << 3);
    uint4 vv = *(const uint4*)&tile[col][c2];
    *(uint4*)(xt + (((size_t)b * 130 + y + 1) * 130 + col + 1) * 128 + cg) = vv;
  }
  if (t < 128) {
    float r = 0.f;
#pragma unroll
    for (int j = 0; j < 8; ++j) r += psum[t][j];
    rowsum[((size_t)b * 128 + t) * 128 + y] = r;
  }
}

// ---------------------------------------------------------------------------
// Kernel 1b: zero the padded borders of xt
// ---------------------------------------------------------------------------
__global__ __launch_bounds__(256) void k_border(unsigned short* __restrict__ xt) {
  const int b = blockIdx.y;
  const int idx = blockIdx.x * 256 + threadIdx.x;
  if (idx >= 8256) return;
  int row, col, ck;
  if (idx < 4160) {
    row = (idx < 2080) ? 0 : 129;
    const int s = idx % 2080;
    col = s >> 4;
    ck = s & 15;
  } else {
    const int s = idx - 4160;
    row = (s >> 5) + 1;
    col = (s & 16) ? 129 : 0;
    ck = s & 15;
  }
  uint4 z = {0, 0, 0, 0};
  *(uint4*)(xt + ((size_t)b * 130 + row) * 130 * 128 + (size_t)col * 128 + ck * 8) = z;
}

// ---------------------------------------------------------------------------
// Kernel 2: rowsums -> pooled -> attention MLP -> softmax -> attn, agg_b
// ---------------------------------------------------------------------------
__global__ __launch_bounds__(128) void k_attn(const float* __restrict__ rowsum,
                                              const float* __restrict__ aw1,
                                              const float* __restrict__ ab1,
                                              const float* __restrict__ aw2,
                                              const float* __restrict__ ab2,
                                              const float* __restrict__ bias,
                                              float* __restrict__ attn,
                                              float* __restrict__ aggb) {
  __shared__ float pooled[128];
  __shared__ float h[32];
  __shared__ float at[4];
  const int b = blockIdx.x, t = threadIdx.x;
  const float* rs = rowsum + (size_t)(b * 128 + t) * 128;
  float s = 0.f;
  for (int yy = 0; yy < 128; ++yy) s += rs[yy];
  pooled[t] = s * (1.f / 16384.f);
  __syncthreads();
  if (t < 32) {
    float hv = ab1[t];
    for (int c = 0; c < 128; ++c) hv += pooled[c] * aw1[t * 128 + c];
    h[t] = fmaxf(hv, 0.f);
  }
  __syncthreads();
  if (t < 4) {
    float sc = ab2[t];
    for (int a = 0; a < 32; ++a) sc += h[a] * aw2[t * 32 + a];
    at[t] = sc * (1.f / 30.f);
  }
  __syncthreads();
  if (t == 0) {
    float m = fmaxf(fmaxf(at[0], at[1]), fmaxf(at[2], at[3]));
    float e0 = __expf(at[0] - m), e1 = __expf(at[1] - m);
    float e2 = __expf(at[2] - m), e3 = __expf(at[3] - m);
    float inv = 1.f / (e0 + e1 + e2 + e3);
    at[0] = e0 * inv; at[1] = e1 * inv; at[2] = e2 * inv; at[3] = e3 * inv;
  }
  __syncthreads();
  if (t < 4) attn[b * 4 + t] = at[t];
  float ab = 0.f;
  for (int k = 0; k < 4; ++k) ab += at[k] * bias[k * 128 + t];
  aggb[b * 128 + t] = ab;
}

// ---------------------------------------------------------------------------
// Kernel 3: aggregate weights over K, bf16, GEMM-A slab layout (linear):
//   aggw[(((b*18 + s)*128 + o)*64 + kk)], tap=s>>1, c=(s&1)*64+kk
// ---------------------------------------------------------------------------
__global__ __launch_bounds__(256) void k_aggw(const float* __restrict__ weight,
                                              const float* __restrict__ attn,
                                              unsigned short* __restrict__ aggw) {
  const int fid = blockIdx.x * 256 + threadIdx.x;
  const int kk = fid & 63;
  const int o = (fid >> 6) & 127;
  const int rest = fid >> 13;      // b*18 + s
  const int s = rest % 18;
  const int b = rest / 18;
  const int c = ((s & 1) << 6) + kk;
  const int pq = s >> 1;
  const size_t src = (size_t)o * 1152 + (size_t)c * 9 + pq;
  float v = attn[b * 4 + 0] * weight[src]
          + attn[b * 4 + 1] * weight[src + 147456]
          + attn[b * 4 + 2] * weight[src + 2 * 147456]
          + attn[b * 4 + 3] * weight[src + 3 * 147456];
  aggw[fid] = f2bf(v);
}

// ---------------------------------------------------------------------------
// Kernel 4: conv implicit GEMM. BM=128(Cout) x BN=256(2 y-rows x 128 cols),
// K=1152 in 18 steps of BK=64. 512 threads / 8 waves (2M x 4N), wave tile
// 64x64. 3-deep LDS pipeline, counted vmcnt(6) (T4), raw s_barrier, T2
// both-sides XOR swizzle (linear LDS dest + inverse-swizzled global source +
// swizzled ds_read), T5 setprio around MFMA clusters.
// ---------------------------------------------------------------------------
__global__ __launch_bounds__(512, 2) void k_conv(const unsigned short* __restrict__ xt,
                                                 const unsigned short* __restrict__ aggw,
                                                 const float* __restrict__ aggb,
                                                 float* __restrict__ out) {
  __shared__ unsigned short lds[3][24576];   // per tile: A[128][64] then B[256][64]
  const int id = blockIdx.x;
  const int swz = (id & 7) * 128 + (id >> 3);   // 1024 % 8 == 0: bijective
  const int b = swz >> 6;
  const int y0 = (swz & 63) * 2;
  const int t = threadIdx.x;
  const int lane = t & 63, w = t >> 6;
  const int mw = w >> 2, nw = w & 3;
  const int l15 = lane & 15, lk = lane >> 4;
  const int rswz = (l15 & 7) * 8;   // ds_read XOR (elements)

  // --- staging assignments (chunk = 16B = 8 elems) -------------------------
  // A: 1024 chunks; wave w covers w*128 + i*64 + lane, i in {0,1}
  const unsigned short* aS[2];
  int aD[2];
#pragma unroll
  for (int i = 0; i < 2; ++i) {
    const int ca = w * 128 + i * 64 + lane;
    const int n = ca >> 3, k8 = ca & 7;
    aS[i] = aggw + (size_t)b * 147456 + n * 64 + ((k8 ^ (n & 7)) * 8);
    aD[i] = w * 1024 + i * 512;
  }
  // B: 2048 chunks; wave w covers w*256 + i*64 + lane, i in {0..3}
  //    chunk -> r = c>>10, n = (c>>3)&127, k8 = c&7
  //    B[r*128+n][kk] = xt[b][y0+r+p][n+q][c0+kk]
  const unsigned short* bS[4];
  int bD[4];
#pragma unroll
  for (int i = 0; i < 4; ++i) {
    const int cb = w * 256 + i * 64 + lane;
    const int r = cb >> 10, n = (cb >> 3) & 127, k8 = cb & 7;
    bS[i] = xt + ((size_t)(b * 130 + y0 + r) * 130 + n) * 128 + ((k8 ^ (n & 7)) * 8);
    bD[i] = 8192 + w * 2048 + i * 512;
  }

#define STAGE(buf, s) {                                                        \
    const int tap_ = (s) >> 1, c0_ = ((s) & 1) << 6;                           \
    const int p_ = tap_ / 3, q_ = tap_ - 3 * p_;                               \
    _Pragma("unroll")                                                          \
    for (int i = 0; i < 2; ++i)                                                \
      async16(aS[i] + (s) * 8192, &lds[buf][0] + aD[i]);                       \
    _Pragma("unroll")                                                          \
    for (int i = 0; i < 4; ++i)                                                \
      async16(bS[i] + p_ * XT_ROW + q_ * 128 + c0_, &lds[buf][0] + bD[i]);     \
  }

  f32x4 acc[4][4] = {};
  STAGE(0, 0);
  STAGE(1, 1);

#pragma unroll
  for (int s = 0; s < 18; ++s) {
    const int cur = s % 3;
    // wait for tile s (keep tile s+1's 6 loads in flight), then sync
    if (s < 17) { asm volatile("s_waitcnt vmcnt(6)" ::: "memory"); }
    else       { asm volatile("s_waitcnt vmcnt(0)" ::: "memory"); }
    __builtin_amdgcn_sched_barrier(0);
    __builtin_amdgcn_s_barrier();
    __builtin_amdgcn_sched_barrier(0);
    if (s + 2 < 18) STAGE((s + 2) % 3, s + 2);
    __builtin_amdgcn_sched_barrier(0);

    const unsigned short* A0 = &lds[cur][0];
    const unsigned short* B0 = &lds[cur][8192];
#pragma unroll
    for (int kk = 0; kk < 2; ++kk) {
      bf16x8 af[4], bfr[4];
#pragma unroll
      for (int mi = 0; mi < 4; ++mi)
        af[mi] = *(const bf16x8*)(A0 + (mw * 64 + mi * 16 + l15) * 64
                                     + ((kk * 32 + lk * 8) ^ rswz));
#pragma unroll
      for (int ni = 0; ni < 4; ++ni)
        bfr[ni] = *(const bf16x8*)(B0 + (nw * 64 + ni * 16 + l15) * 64
                                      + ((kk * 32 + lk * 8) ^ rswz));
      __builtin_amdgcn_s_setprio(1);
#pragma unroll
      for (int mi = 0; mi < 4; ++mi)
#pragma unroll
        for (int ni = 0; ni < 4; ++ni)
          acc[mi][ni] = __builtin_amdgcn_mfma_f32_16x16x32_bf16(af[mi], bfr[ni], acc[mi][ni], 0, 0, 0);
      __builtin_amdgcn_s_setprio(0);
    }
  }
#undef STAGE

  // epilogue: wave (mw,nw): r = nw>>1, y = y0+r, colb = (nw&1)*64 + l15
  const int r_ = nw >> 1;
  const int y = y0 + r_;
  const int colb = (nw & 1) * 64 + l15;
#pragma unroll
  for (int mi = 0; mi < 4; ++mi) {
    const int o = mw * 64 + mi * 16 + lk * 4;
#pragma unroll
    for (int rr = 0; rr < 4; ++rr) {
      const float bsv = aggb[b * 128 + o + rr];
      float* orow = out + ((size_t)(b * 128 + o + rr) * 128 + y) * 128 + colb;
      orow[0]  = acc[mi][0][rr] + bsv;
      orow[16] = acc[mi][1][rr] + bsv;
      orow[32] = acc[mi][2][rr] + bsv;
      orow[48] = acc[mi][3][rr] + bsv;
    }
  }
}

// ---------------------------------------------------------------------------
extern "C" void kernel_launch(void* const* d_in, const int* in_sizes, int n_in,
                              void* d_out, int out_size, void* d_ws, size_t ws_size,
                              hipStream_t stream) {
  const float* x      = (const float*)d_in[0];
  const float* weight = (const float*)d_in[1];
  const float* bias   = (const float*)d_in[2];
  const float* aw1    = (const float*)d_in[3];
  const float* ab1    = (const float*)d_in[4];
  const float* aw2    = (const float*)d_in[5];
  const float* ab2    = (const float*)d_in[6];
  float* out = (float*)d_out;

  char* ws = (char*)d_ws;
  unsigned short* xt   = (unsigned short*)ws;                        // 69,222,400 B
  unsigned short* aggw = (unsigned short*)(ws + 69222400);           //  4,718,592 B
  float* rowsum        = (float*)(ws + 69222400 + 4718592);          //  1,048,576 B
  float* attn          = (float*)(ws + 69222400 + 4718592 + 1048576);         // 256 B
  float* aggb          = (float*)(ws + 69222400 + 4718592 + 1048576 + 256);   // 8 KB

  hipLaunchKernelGGL(k_border, dim3(33, 16), dim3(256), 0, stream, xt);
  hipLaunchKernelGGL(k_transpose, dim3(128, 16), dim3(256), 0, stream, x, xt, rowsum);
  hipLaunchKernelGGL(k_attn, dim3(16), dim3(128), 0, stream,
                     rowsum, aw1, ab1, aw2, ab2, bias, attn, aggb);
  hipLaunchKernelGGL(k_aggw, dim3(9216), dim3(256), 0, stream, weight, attn, aggw);
  hipLaunchKernelGGL(k_conv, dim3(1024), dim3(512), 0, stream, xt, aggw, aggb, out);
}

// Round 6
// 149.728 us; speedup vs baseline: 1.9962x; 1.0572x over previous
//
#include <hip/hip_runtime.h>

typedef float f32x4 __attribute__((ext_vector_type(4)));
typedef short bf16x8 __attribute__((ext_vector_type(8)));

__device__ __forceinline__ unsigned short f2bf(float f) {
  unsigned u = __builtin_bit_cast(unsigned, f);
  u = (u + 0x7FFFu + ((u >> 16) & 1u)) >> 16;
  return (unsigned short)u;
}

// async global->LDS, 16B per lane. LDS dest = wave-uniform base + lane*16B.
__device__ __forceinline__ void async16(const unsigned short* g, unsigned short* l) {
  __builtin_amdgcn_global_load_lds(
      (__attribute__((address_space(1))) void*)g,
      (__attribute__((address_space(3))) void*)l, 16, 0, 0);
}

// xt padded layout: [b][row 0..129][col 0..129][ch 0..127] bf16, borders zero.
#define XT_ROW 16640              // 130*128 elems per padded row

// ---------------------------------------------------------------------------
// Kernel 1: x (B,C,H,W) f32 -> xt padded bf16 [b][y+1][col+1][c], + row sums
// ---------------------------------------------------------------------------
__global__ __launch_bounds__(256) void k_transpose(const float* __restrict__ x,
                                                   unsigned short* __restrict__ xt,
                                                   float* __restrict__ rowsum) {
  __shared__ unsigned short tile[128][128];
  __shared__ float psum[128][8];
  const int y = blockIdx.x, b = blockIdx.y;
  const int t = threadIdx.x;
  const int colb = (t & 7) * 16;
  const int cp = t >> 3;
  const int swz = (t & 7) << 3;
  for (int ci = 0; ci < 4; ++ci) {
    const int c = ci * 32 + cp;
    const int c2 = c ^ swz;
    const float* src = x + (((size_t)(b * 128 + c) * 128 + y) * 128 + colb);
    float s = 0.f;
#pragma unroll
    for (int j = 0; j < 16; j += 4) {
      float4 v = *(const float4*)(src + j);
      s += v.x + v.y + v.z + v.w;
      tile[colb + j + 0][c2] = f2bf(v.x);
      tile[colb + j + 1][c2] = f2bf(v.y);
      tile[colb + j + 2][c2] = f2bf(v.z);
      tile[colb + j + 3][c2] = f2bf(v.w);
    }
    psum[c][t & 7] = s;
  }
  __syncthreads();
#pragma unroll
  for (int it = 0; it < 8; ++it) {
    const int slot = t + it * 256;
    const int col = slot >> 4;
    const int cg = (slot & 15) * 8;
    const int c2 = cg ^ (((col >> 4) & 7) << 3);
    uint4 vv = *(const uint4*)&tile[col][c2];
    *(uint4*)(xt + (((size_t)b * 130 + y + 1) * 130 + col + 1) * 128 + cg) = vv;
  }
  if (t < 128) {
    float r = 0.f;
#pragma unroll
    for (int j = 0; j < 8; ++j) r += psum[t][j];
    rowsum[((size_t)b * 128 + t) * 128 + y] = r;
  }
}

// ---------------------------------------------------------------------------
// Kernel 1b: zero the padded borders of xt
// ---------------------------------------------------------------------------
__global__ __launch_bounds__(256) void k_border(unsigned short* __restrict__ xt) {
  const int b = blockIdx.y;
  const int idx = blockIdx.x * 256 + threadIdx.x;
  if (idx >= 8256) return;
  int row, col, ck;
  if (idx < 4160) {
    row = (idx < 2080) ? 0 : 129;
    const int s = idx % 2080;
    col = s >> 4;
    ck = s & 15;
  } else {
    const int s = idx - 4160;
    row = (s >> 5) + 1;
    col = (s & 16) ? 129 : 0;
    ck = s & 15;
  }
  uint4 z = {0, 0, 0, 0};
  *(uint4*)(xt + ((size_t)b * 130 + row) * 130 * 128 + (size_t)col * 128 + ck * 8) = z;
}

// ---------------------------------------------------------------------------
// Kernel 2: rowsums -> pooled -> attention MLP -> softmax -> attn, agg_b
// ---------------------------------------------------------------------------
__global__ __launch_bounds__(128) void k_attn(const float* __restrict__ rowsum,
                                              const float* __restrict__ aw1,
                                              const float* __restrict__ ab1,
                                              const float* __restrict__ aw2,
                                              const float* __restrict__ ab2,
                                              const float* __restrict__ bias,
                                              float* __restrict__ attn,
                                              float* __restrict__ aggb) {
  __shared__ float pooled[128];
  __shared__ float h[32];
  __shared__ float at[4];
  const int b = blockIdx.x, t = threadIdx.x;
  const float* rs = rowsum + (size_t)(b * 128 + t) * 128;
  float s = 0.f;
  for (int yy = 0; yy < 128; ++yy) s += rs[yy];
  pooled[t] = s * (1.f / 16384.f);
  __syncthreads();
  if (t < 32) {
    float hv = ab1[t];
    for (int c = 0; c < 128; ++c) hv += pooled[c] * aw1[t * 128 + c];
    h[t] = fmaxf(hv, 0.f);
  }
  __syncthreads();
  if (t < 4) {
    float sc = ab2[t];
    for (int a = 0; a < 32; ++a) sc += h[a] * aw2[t * 32 + a];
    at[t] = sc * (1.f / 30.f);
  }
  __syncthreads();
  if (t == 0) {
    float m = fmaxf(fmaxf(at[0], at[1]), fmaxf(at[2], at[3]));
    float e0 = __expf(at[0] - m), e1 = __expf(at[1] - m);
    float e2 = __expf(at[2] - m), e3 = __expf(at[3] - m);
    float inv = 1.f / (e0 + e1 + e2 + e3);
    at[0] = e0 * inv; at[1] = e1 * inv; at[2] = e2 * inv; at[3] = e3 * inv;
  }
  __syncthreads();
  if (t < 4) attn[b * 4 + t] = at[t];
  float ab = 0.f;
  for (int k = 0; k < 4; ++k) ab += at[k] * bias[k * 128 + t];
  aggb[b * 128 + t] = ab;
}

// ---------------------------------------------------------------------------
// Kernel 3: aggregate weights over K, bf16, slab layout for BK=32:
//   aggw[(((b*36 + s)*128 + o)*32 + kk)], tap = s>>2, c = (s&3)*32 + kk
// ---------------------------------------------------------------------------
__global__ __launch_bounds__(256) void k_aggw(const float* __restrict__ weight,
                                              const float* __restrict__ attn,
                                              unsigned short* __restrict__ aggw) {
  const int fid = blockIdx.x * 256 + threadIdx.x;
  const int kk = fid & 31;
  const int o = (fid >> 5) & 127;
  const int rest = fid >> 12;      // b*36 + s
  const int s = rest % 36;
  const int b = rest / 36;
  const int c = ((s & 3) << 5) + kk;
  const int pq = s >> 2;
  const size_t src = (size_t)o * 1152 + (size_t)c * 9 + pq;
  float v = attn[b * 4 + 0] * weight[src]
          + attn[b * 4 + 1] * weight[src + 147456]
          + attn[b * 4 + 2] * weight[src + 2 * 147456]
          + attn[b * 4 + 3] * weight[src + 3 * 147456];
  aggw[fid] = f2bf(v);
}

// ---------------------------------------------------------------------------
// Kernel 4: conv implicit GEMM. BM=128 x BN=128 (1 y-row), BK=32, 36 steps.
// 256 threads / 4 waves (2x2), wave tile 64x64. 3-deep LDS pipeline (48 KB
// -> 3 blocks/CU for implicit cross-block overlap), counted vmcnt(4) (T4),
// raw s_barrier, T2 both-sides XOR swizzle (4-slot, residual 2-way = free),
// T5 setprio. Tile: A[128][32] @0, B[128][32] @4096 elems.
// ---------------------------------------------------------------------------
__global__ __launch_bounds__(256, 3) void k_conv(const unsigned short* __restrict__ xt,
                                                 const unsigned short* __restrict__ aggw,
                                                 const float* __restrict__ aggb,
                                                 float* __restrict__ out) {
  __shared__ unsigned short lds[3][8192];
  const int id = blockIdx.x;
  const int swz = (id & 7) * 256 + (id >> 3);   // 2048 % 8 == 0: bijective
  const int b = swz >> 7, y = swz & 127;
  const int t = threadIdx.x;
  const int lane = t & 63, w = t >> 6;
  const int mw = w >> 1, nw = w & 1;
  const int l15 = lane & 15, lk = lane >> 4;
  const int rswz = (l15 & 3) * 8;   // read-side XOR (elems)

  // staging: chunk = 16B = 8 elems; tile rows n, slot k8 in 0..3
  // thread t covers chunks {t, t+256} for A and for B.
  const unsigned short* aS[2];
  const unsigned short* bS[2];
  int dA[2], dB[2];
#pragma unroll
  for (int i = 0; i < 2; ++i) {
    const int c = i * 256 + t;
    const int n = c >> 2, k8 = c & 3;
    const int sk = (k8 ^ (n & 3)) * 8;          // inverse-swizzled source slot
    aS[i] = aggw + (size_t)b * 147456 + n * 32 + sk;
    bS[i] = xt + ((size_t)(b * 130 + y) * 130 + n) * 128 + sk;
    dA[i] = i * 2048 + w * 512;                 // wave-uniform dest (elems)
    dB[i] = 4096 + i * 2048 + w * 512;
  }

#define STAGE(buf, s) {                                                        \
    const int tap_ = (s) >> 2, c0_ = ((s) & 3) << 5;                           \
    const int p_ = tap_ / 3, q_ = tap_ - 3 * p_;                               \
    async16(aS[0] + (s) * 4096, &lds[buf][0] + dA[0]);                         \
    async16(aS[1] + (s) * 4096, &lds[buf][0] + dA[1]);                         \
    async16(bS[0] + p_ * XT_ROW + q_ * 128 + c0_, &lds[buf][0] + dB[0]);       \
    async16(bS[1] + p_ * XT_ROW + q_ * 128 + c0_, &lds[buf][0] + dB[1]);       \
  }

  f32x4 acc[4][4] = {};
  STAGE(0, 0);
  STAGE(1, 1);

#pragma unroll
  for (int s = 0; s < 36; ++s) {
    const int cur = s % 3;
    if (s < 35) { asm volatile("s_waitcnt vmcnt(4)" ::: "memory"); }
    else        { asm volatile("s_waitcnt vmcnt(0)" ::: "memory"); }
    __builtin_amdgcn_sched_barrier(0);
    __builtin_amdgcn_s_barrier();
    __builtin_amdgcn_sched_barrier(0);
    if (s + 2 < 36) STAGE((s + 2) % 3, s + 2);
    __builtin_amdgcn_sched_barrier(0);

    const unsigned short* A0 = &lds[cur][0];
    const unsigned short* B0 = &lds[cur][4096];
    bf16x8 af[4], bfr[4];
#pragma unroll
    for (int mi = 0; mi < 4; ++mi) {
      const int row = mw * 64 + mi * 16 + l15;
      af[mi] = *(const bf16x8*)(A0 + row * 32 + ((lk * 8) ^ rswz));
    }
#pragma unroll
    for (int ni = 0; ni < 4; ++ni) {
      const int row = nw * 64 + ni * 16 + l15;
      bfr[ni] = *(const bf16x8*)(B0 + row * 32 + ((lk * 8) ^ rswz));
    }
    __builtin_amdgcn_s_setprio(1);
#pragma unroll
    for (int mi = 0; mi < 4; ++mi)
#pragma unroll
      for (int ni = 0; ni < 4; ++ni)
        acc[mi][ni] = __builtin_amdgcn_mfma_f32_16x16x32_bf16(af[mi], bfr[ni], acc[mi][ni], 0, 0, 0);
    __builtin_amdgcn_s_setprio(0);
  }
#undef STAGE

  // epilogue: C/D col = lane&15 (n/px), row = (lane>>4)*4 + r (Cout)
  const int colb = nw * 64 + l15;
#pragma unroll
  for (int mi = 0; mi < 4; ++mi) {
    const int o = mw * 64 + mi * 16 + lk * 4;
#pragma unroll
    for (int rr = 0; rr < 4; ++rr) {
      const float bsv = aggb[b * 128 + o + rr];
      float* orow = out + ((size_t)(b * 128 + o + rr) * 128 + y) * 128 + colb;
      orow[0]  = acc[mi][0][rr] + bsv;
      orow[16] = acc[mi][1][rr] + bsv;
      orow[32] = acc[mi][2][rr] + bsv;
      orow[48] = acc[mi][3][rr] + bsv;
    }
  }
}

// ---------------------------------------------------------------------------
extern "C" void kernel_launch(void* const* d_in, const int* in_sizes, int n_in,
                              void* d_out, int out_size, void* d_ws, size_t ws_size,
                              hipStream_t stream) {
  const float* x      = (const float*)d_in[0];
  const float* weight = (const float*)d_in[1];
  const float* bias   = (const float*)d_in[2];
  const float* aw1    = (const float*)d_in[3];
  const float* ab1    = (const float*)d_in[4];
  const float* aw2    = (const float*)d_in[5];
  const float* ab2    = (const float*)d_in[6];
  float* out = (float*)d_out;

  char* ws = (char*)d_ws;
  unsigned short* xt   = (unsigned short*)ws;                        // 69,222,400 B
  unsigned short* aggw = (unsigned short*)(ws + 69222400);           //  4,718,592 B
  float* rowsum        = (float*)(ws + 69222400 + 4718592);          //  1,048,576 B
  float* attn          = (float*)(ws + 69222400 + 4718592 + 1048576);         // 256 B
  float* aggb          = (float*)(ws + 69222400 + 4718592 + 1048576 + 256);   // 8 KB

  hipLaunchKernelGGL(k_border, dim3(33, 16), dim3(256), 0, stream, xt);
  hipLaunchKernelGGL(k_transpose, dim3(128, 16), dim3(256), 0, stream, x, xt, rowsum);
  hipLaunchKernelGGL(k_attn, dim3(16), dim3(128), 0, stream,
                     rowsum, aw1, ab1, aw2, ab2, bias, attn, aggb);
  hipLaunchKernelGGL(k_aggw, dim3(9216), dim3(256), 0, stream, weight, attn, aggw);
  hipLaunchKernelGGL(k_conv, dim3(2048), dim3(256), 0, stream, xt, aggw, aggb, out);
}